// Round 4
// baseline (77.969 us; speedup 1.0000x reference)
//
#include <hip/hip_runtime.h>
#include <hip/hip_bf16.h>

#define S_ 8192
#define H_ 8
#define D_ 64
#define M_ 64
#define BH_ 32
#define CPK_ 80          // buf1/partial row stride (c 0..79, den at c=64)
#define NCHQ 16
#define TILE 64
#define QTILES (S_ / NCHQ / TILE)   // 8

typedef short bf16x8 __attribute__((ext_vector_type(8)));
typedef float f32x4 __attribute__((ext_vector_type(4)));

constexpr float XS_ = 0.35355339059327373f * 1.4426950408889634f; // D^-1/4 * log2(e)
constexpr float HS_ = 0.34657359027997264f;                        // ln2/2
constexpr float EPS_ = 1e-6f;

__device__ __forceinline__ unsigned short f2bf(float f) {
    unsigned int u = __float_as_uint(f);
    u += 0x7FFFu + ((u >> 16) & 1u);          // RNE
    return (unsigned short)(u >> 16);
}
// paired RNE conversion -> v_cvt_pk_bf16_f32 (lo in low 16 bits)
__device__ __forceinline__ unsigned int pkbf(float lo, float hi) {
    __hip_bfloat162 t = __float22bfloat162_rn(float2{lo, hi});
    return *reinterpret_cast<unsigned int*>(&t);
}
__device__ __forceinline__ float fexp2(float x) { return __builtin_amdgcn_exp2f(x); }

#define MFMA(a, b, c) __builtin_amdgcn_mfma_f32_16x16x32_bf16((a), (b), (c), 0, 0, 0)
#define SWZ(byteoff, row) ((byteoff) ^ (((row) & 7) << 4))

// ---------------------------------------------------------------------------
// Phase K: per (chunk, bh) block. 4 waves; wave owns a 16-row strip for the
// P pass and the m-tile (wid) for buf1 accumulation (no cross-wave reduce).
//   P[row][m] = mfma(Kscaled, projT) ; e = exp2(P - h)
//   buf1[m][c] += mfma(E_T, [V,1])   via LDS-transposed eT[m][row], vT[c][row]
// ---------------------------------------------------------------------------
__global__ void __launch_bounds__(256)
fa_k(const float* __restrict__ ks, const float* __restrict__ vs,
     const float* __restrict__ proj, float* __restrict__ partial,
     int nch, int ktiles)
{
    const int chunk = blockIdx.x;
    const int bh    = blockIdx.y;
    const int b = bh >> 3, h = bh & 7;
    const int tid = threadIdx.x, wid = tid >> 6, lane = tid & 63;
    const int l15 = lane & 15, g = lane >> 4;

    __shared__ __align__(16) char eTb[2][M_ * TILE * 2];   // [m][row] bf16, swz by m
    __shared__ __align__(16) char vTb[2][D_ * TILE * 2];   // [c][row] bf16, swz by c

    const int rows = ktiles * TILE;
    const int s0 = chunk * rows;
    const size_t rs = (size_t)H_ * D_;
    const float* kb = ks + ((size_t)b * S_ * H_ + h) * D_;
    const float* vb = vs + ((size_t)b * S_ * H_ + h) * D_;

    // proj B-fragments: B[k=d][n=m]: lane: m = mt*16+l15, d = g*8+j (+32*kk)
    bf16x8 pf[4][2];
#pragma unroll
    for (int mt = 0; mt < 4; ++mt)
#pragma unroll
        for (int kk = 0; kk < 2; ++kk) {
            const float* p = proj + (mt * 16 + l15) * D_ + kk * 32 + g * 8;
            float4 a = *(const float4*)p, c = *(const float4*)(p + 4);
            bf16x8 f;
            f[0] = (short)f2bf(a.x); f[1] = (short)f2bf(a.y);
            f[2] = (short)f2bf(a.z); f[3] = (short)f2bf(a.w);
            f[4] = (short)f2bf(c.x); f[5] = (short)f2bf(c.y);
            f[6] = (short)f2bf(c.z); f[7] = (short)f2bf(c.w);
            pf[mt][kk] = f;
        }

    // ones-column B-frag (c-tile 4): B[k][c]=1 iff c==64  (lane l15==0)
    bf16x8 onef = {0, 0, 0, 0, 0, 0, 0, 0};
    if (l15 == 0) {
#pragma unroll
        for (int j = 0; j < 8; ++j) onef[j] = (short)0x3F80;
    }

    f32x4 acc[5];
#pragma unroll
    for (int ci = 0; ci < 5; ++ci) acc[ci] = (f32x4){0.f, 0.f, 0.f, 0.f};

    auto loadT = [&](int t, float4* kp, float* vp) {
        int sb = s0 + t * TILE;
        const float* krow = kb + (size_t)(sb + wid * 16 + l15) * rs;
        kp[0] = *(const float4*)(krow + g * 8);
        kp[1] = *(const float4*)(krow + g * 8 + 4);
        kp[2] = *(const float4*)(krow + 32 + g * 8);
        kp[3] = *(const float4*)(krow + 32 + g * 8 + 4);
        const float* vcol = vb + lane;
        int rb = sb + wid * 16;
#pragma unroll
        for (int r = 0; r < 16; ++r)
            vp[r] = vcol[(size_t)(rb + r) * rs];
    };

    auto body = [&](int t, int p, const float4* kc, const float* vc,
                    float4* kn, float* vn) {
        if (t + 1 < ktiles) loadT(t + 1, kn, vn);

        // scale + h for row (wid*16 + l15)
        float kx[16];
#pragma unroll
        for (int i = 0; i < 4; ++i) {
            kx[4 * i + 0] = kc[i].x * XS_; kx[4 * i + 1] = kc[i].y * XS_;
            kx[4 * i + 2] = kc[i].z * XS_; kx[4 * i + 3] = kc[i].w * XS_;
        }
        float sq = 0.f;
#pragma unroll
        for (int j = 0; j < 16; ++j) sq += kx[j] * kx[j];
        sq += __shfl_xor(sq, 16);
        sq += __shfl_xor(sq, 32);
        float hrow = sq * HS_ + 3.0f;

        union { bf16x8 v; unsigned int u[4]; } A0, A1;
#pragma unroll
        for (int i = 0; i < 4; ++i) {
            A0.u[i] = pkbf(kx[2 * i], kx[2 * i + 1]);
            A1.u[i] = pkbf(kx[8 + 2 * i], kx[9 + 2 * i]);
        }

        f32x4 pa[4];
#pragma unroll
        for (int mt = 0; mt < 4; ++mt) {
            pa[mt] = (f32x4){0.f, 0.f, 0.f, 0.f};
            pa[mt] = MFMA(A0.v, pf[mt][0], pa[mt]);
            pa[mt] = MFMA(A1.v, pf[mt][1], pa[mt]);
        }

        float hr[4];
#pragma unroll
        for (int r = 0; r < 4; ++r) hr[r] = __shfl(hrow, 4 * g + r);

        char* etp = eTb[p];
        char* vtp = vTb[p];
#pragma unroll
        for (int mt = 0; mt < 4; ++mt) {
            float e0 = fexp2(pa[mt][0] - hr[0]);
            float e1 = fexp2(pa[mt][1] - hr[1]);
            float e2 = fexp2(pa[mt][2] - hr[2]);
            float e3 = fexp2(pa[mt][3] - hr[3]);
            unsigned long long pk = (unsigned long long)pkbf(e0, e1)
                                  | ((unsigned long long)pkbf(e2, e3) << 32);
            int m = mt * 16 + l15;
            *(unsigned long long*)(etp + SWZ(m * 128 + 32 * wid + 8 * g, m)) = pk;
        }
        {
            int c = lane;
            union { bf16x8 v; unsigned int u[4]; } W0, W1;
#pragma unroll
            for (int i = 0; i < 4; ++i) {
                W0.u[i] = pkbf(vc[2 * i], vc[2 * i + 1]);
                W1.u[i] = pkbf(vc[8 + 2 * i], vc[9 + 2 * i]);
            }
            *(bf16x8*)(vtp + SWZ(c * 128 + 32 * wid, c)) = W0.v;
            *(bf16x8*)(vtp + SWZ(c * 128 + 32 * wid + 16, c)) = W1.v;
        }
        __syncthreads();

        bf16x8 a2[2];
        {
            int m = wid * 16 + l15;
            a2[0] = *(const bf16x8*)(etp + SWZ(m * 128 + 16 * g, m));
            a2[1] = *(const bf16x8*)(etp + SWZ(m * 128 + 16 * g + 64, m));
        }
#pragma unroll
        for (int ci = 0; ci < 4; ++ci) {
            int c = ci * 16 + l15;
            bf16x8 b0 = *(const bf16x8*)(vtp + SWZ(c * 128 + 16 * g, c));
            bf16x8 b1 = *(const bf16x8*)(vtp + SWZ(c * 128 + 16 * g + 64, c));
            acc[ci] = MFMA(a2[0], b0, acc[ci]);
            acc[ci] = MFMA(a2[1], b1, acc[ci]);
        }
        acc[4] = MFMA(a2[0], onef, acc[4]);
        acc[4] = MFMA(a2[1], onef, acc[4]);
    };

    float4 ka[4], kb2[4];
    float va[16], vb2[16];
    loadT(0, ka, va);
    for (int t = 0; t + 2 <= ktiles; t += 2) {
        body(t, 0, ka, va, kb2, vb2);
        body(t + 1, 1, kb2, vb2, ka, va);
    }

    // store partials: D[m][c]: m = wid*16 + 4g + r, c = ci*16 + l15
    float* dst = partial + ((size_t)bh * nch + chunk) * (M_ * CPK_);
#pragma unroll
    for (int ci = 0; ci < 5; ++ci)
#pragma unroll
        for (int r = 0; r < 4; ++r)
            dst[(wid * 16 + 4 * g + r) * CPK_ + ci * 16 + l15] = acc[ci][r];
}

// ---------------------------------------------------------------------------
// Reduce partials over chunks -> buf1[bh][m][CPK_]
// ---------------------------------------------------------------------------
__global__ void __launch_bounds__(256)
fa_r(const float* __restrict__ partial, float* __restrict__ buf1, int nch)
{
    int e = blockIdx.x * 256 + threadIdx.x;
    if (e >= BH_ * M_ * CPK_) return;
    int bh = e / (M_ * CPK_);
    int r  = e - bh * (M_ * CPK_);
    const float* src = partial + (size_t)bh * nch * (M_ * CPK_) + r;
    float s0 = 0.f, s1 = 0.f, s2 = 0.f, s3 = 0.f;
    int ch = 0;
    for (; ch + 4 <= nch; ch += 4) {
        s0 += src[(size_t)(ch + 0) * (M_ * CPK_)];
        s1 += src[(size_t)(ch + 1) * (M_ * CPK_)];
        s2 += src[(size_t)(ch + 2) * (M_ * CPK_)];
        s3 += src[(size_t)(ch + 3) * (M_ * CPK_)];
    }
    for (; ch < nch; ++ch) s0 += src[(size_t)ch * (M_ * CPK_)];
    buf1[e] = (s0 + s1) + (s2 + s3);
}

// ---------------------------------------------------------------------------
// Phase Q: P = mfma(Qscaled, projT); e = exp2(P - h);
// Out^T-tiles: D[c][qrow] = mfma(buf1T, E_T); den = row c=64; out = num/den.
// ---------------------------------------------------------------------------
__global__ void __launch_bounds__(256)
fa_q(const float* __restrict__ qs, const float* __restrict__ proj,
     const float* __restrict__ buf1, float* __restrict__ out)
{
    const int chunk = blockIdx.x;
    const int bh    = blockIdx.y;
    const int b = bh >> 3, h = bh & 7;
    const int tid = threadIdx.x, wid = tid >> 6, lane = tid & 63;
    const int l15 = lane & 15, g = lane >> 4;

    __shared__ __align__(16) char eLb[2][TILE * M_ * 2];   // [qrow][m] bf16, swz by qrow
    __shared__ __align__(16) char b1tb[CPK_ * M_ * 2];     // [c][m] bf16, swz by c

    const int rows = S_ / NCHQ;
    const int s0 = chunk * rows;
    const size_t rs = (size_t)H_ * D_;
    const float* qb = qs + ((size_t)b * S_ * H_ + h) * D_;

    // stage buf1^T into LDS (c rows 65..79 are zeros in buf1 already)
    const float* b1 = buf1 + (size_t)bh * (M_ * CPK_);
    for (int i = tid; i < M_ * CPK_; i += 256) {
        int m = i / CPK_, c = i - m * CPK_;
        *(unsigned short*)(b1tb + SWZ(c * 128 + 2 * m, c)) = f2bf(b1[i]);
    }

    bf16x8 pf[4][2];
#pragma unroll
    for (int mt = 0; mt < 4; ++mt)
#pragma unroll
        for (int kk = 0; kk < 2; ++kk) {
            const float* p = proj + (mt * 16 + l15) * D_ + kk * 32 + g * 8;
            float4 a = *(const float4*)p, c = *(const float4*)(p + 4);
            bf16x8 f;
            f[0] = (short)f2bf(a.x); f[1] = (short)f2bf(a.y);
            f[2] = (short)f2bf(a.z); f[3] = (short)f2bf(a.w);
            f[4] = (short)f2bf(c.x); f[5] = (short)f2bf(c.y);
            f[6] = (short)f2bf(c.z); f[7] = (short)f2bf(c.w);
            pf[mt][kk] = f;
        }
    __syncthreads();

    // buf1^T A-fragments, read once: A[c][m]: c = ci*16+l15, m = g*8+j (+32*kk)
    bf16x8 af3[5][2];
#pragma unroll
    for (int ci = 0; ci < 5; ++ci)
#pragma unroll
        for (int kk = 0; kk < 2; ++kk) {
            int c = ci * 16 + l15;
            af3[ci][kk] = *(const bf16x8*)(b1tb + SWZ(c * 128 + 16 * g + 64 * kk, c));
        }

    auto loadQ = [&](int t, float4* qp) {
        int sb = s0 + t * TILE;
        const float* qrow = qb + (size_t)(sb + wid * 16 + l15) * rs;
        qp[0] = *(const float4*)(qrow + g * 8);
        qp[1] = *(const float4*)(qrow + g * 8 + 4);
        qp[2] = *(const float4*)(qrow + 32 + g * 8);
        qp[3] = *(const float4*)(qrow + 32 + g * 8 + 4);
    };

    auto body = [&](int t, int p, const float4* qc, float4* qn) {
        if (t + 1 < QTILES) loadQ(t + 1, qn);

        float kx[16];
#pragma unroll
        for (int i = 0; i < 4; ++i) {
            kx[4 * i + 0] = qc[i].x * XS_; kx[4 * i + 1] = qc[i].y * XS_;
            kx[4 * i + 2] = qc[i].z * XS_; kx[4 * i + 3] = qc[i].w * XS_;
        }
        float sq = 0.f;
#pragma unroll
        for (int j = 0; j < 16; ++j) sq += kx[j] * kx[j];
        sq += __shfl_xor(sq, 16);
        sq += __shfl_xor(sq, 32);
        float hrow = sq * HS_ + 3.0f;

        union { bf16x8 v; unsigned int u[4]; } A0, A1;
#pragma unroll
        for (int i = 0; i < 4; ++i) {
            A0.u[i] = pkbf(kx[2 * i], kx[2 * i + 1]);
            A1.u[i] = pkbf(kx[8 + 2 * i], kx[9 + 2 * i]);
        }

        f32x4 pa[4];
#pragma unroll
        for (int mt = 0; mt < 4; ++mt) {
            pa[mt] = (f32x4){0.f, 0.f, 0.f, 0.f};
            pa[mt] = MFMA(A0.v, pf[mt][0], pa[mt]);
            pa[mt] = MFMA(A1.v, pf[mt][1], pa[mt]);
        }

        float hr[4];
#pragma unroll
        for (int r = 0; r < 4; ++r) hr[r] = __shfl(hrow, 4 * g + r);

        char* elp = eLb[p];
#pragma unroll
        for (int mt = 0; mt < 4; ++mt) {
            int m = mt * 16 + l15;
#pragma unroll
            for (int r = 0; r < 4; ++r) {
                float e = fexp2(pa[mt][r] - hr[r]);
                int qrow = wid * 16 + 4 * g + r;
                *(unsigned short*)(elp + SWZ(qrow * 128 + 2 * m, qrow)) = f2bf(e);
            }
        }
        __syncthreads();

        bf16x8 b3[2];
        {
            int qrow = wid * 16 + l15;
            b3[0] = *(const bf16x8*)(elp + SWZ(qrow * 128 + 16 * g, qrow));
            b3[1] = *(const bf16x8*)(elp + SWZ(qrow * 128 + 16 * g + 64, qrow));
        }
        f32x4 dt[5];
#pragma unroll
        for (int ci = 0; ci < 5; ++ci) {
            dt[ci] = (f32x4){0.f, 0.f, 0.f, 0.f};
            dt[ci] = MFMA(af3[ci][0], b3[0], dt[ci]);
            dt[ci] = MFMA(af3[ci][1], b3[1], dt[ci]);
        }

        float den = __shfl(dt[4][0], l15);      // lanes g==0 hold den[qrow=l15]
        float rd = 1.0f / fmaxf(den, EPS_);

        int sg = s0 + t * TILE + wid * 16 + l15;
        size_t base = (((size_t)b * S_ + sg) * H_ + h) * D_;
#pragma unroll
        for (int ci = 0; ci < 4; ++ci) {
            f32x4 o;
#pragma unroll
            for (int r = 0; r < 4; ++r) o[r] = dt[ci][r] * rd;
            *(f32x4*)(out + base + ci * 16 + 4 * g) = o;
        }
    };

    float4 qa[4], qb2[4];
    loadQ(0, qa);
    for (int t = 0; t < QTILES; t += 2) {
        body(t, 0, qa, qb2);
        body(t + 1, 1, qb2, qa);
    }
}

extern "C" void kernel_launch(void* const* d_in, const int* in_sizes, int n_in,
                              void* d_out, int out_size, void* d_ws, size_t ws_size,
                              hipStream_t stream)
{
    const float* qs   = (const float*)d_in[0];
    const float* ks   = (const float*)d_in[1];
    const float* vs   = (const float*)d_in[2];
    const float* proj = (const float*)d_in[3];
    float* out = (float*)d_out;

    // chunks for phase K: prefer 32 (4+ blocks/CU); shrink if ws is tight
    int nch = 32;
    while (nch > 16 &&
           (size_t)BH_ * (size_t)(nch + 1) * (M_ * CPK_) * sizeof(float) > ws_size)
        nch >>= 1;
    int ktiles = S_ / nch / TILE;                 // 4 (or 8)

    float* partial = (float*)d_ws;                // BH*nch*M*CPK
    float* buf1 = partial + (size_t)BH_ * nch * (M_ * CPK_);

    fa_k<<<dim3(nch, BH_), 256, 0, stream>>>(ks, vs, proj, partial, nch, ktiles);
    int nred = (BH_ * M_ * CPK_ + 255) / 256;
    fa_r<<<dim3(nred), 256, 0, stream>>>(partial, buf1, nch);
    fa_q<<<dim3(NCHQ, BH_), 256, 0, stream>>>(qs, proj, buf1, out);
}

// Round 5
// 72.789 us; speedup vs baseline: 1.0712x; 1.0712x over previous
//
#include <hip/hip_runtime.h>
#include <hip/hip_bf16.h>

#define S_ 8192
#define H_ 8
#define D_ 64
#define M_ 64
#define BH_ 32
#define CPK_ 80          // buf1/partial row stride (c 0..79, den at c=64)
#define NCHQ 16
#define TILE 64
#define QTILES (S_ / NCHQ / TILE)   // 8

typedef short bf16x8 __attribute__((ext_vector_type(8)));
typedef float f32x4 __attribute__((ext_vector_type(4)));

constexpr float XS_ = 0.35355339059327373f * 1.4426950408889634f; // D^-1/4 * log2(e)
constexpr float HS_ = 0.34657359027997264f;                        // ln2/2
constexpr float EPS_ = 1e-6f;

__device__ __forceinline__ unsigned short f2bf(float f) {
    unsigned int u = __float_as_uint(f);
    u += 0x7FFFu + ((u >> 16) & 1u);          // RNE
    return (unsigned short)(u >> 16);
}
// paired RNE conversion -> v_cvt_pk_bf16_f32 (lo in low 16 bits)
__device__ __forceinline__ unsigned int pkbf(float lo, float hi) {
    __hip_bfloat162 t = __float22bfloat162_rn(float2{lo, hi});
    return *reinterpret_cast<unsigned int*>(&t);
}
__device__ __forceinline__ float fexp2(float x) { return __builtin_amdgcn_exp2f(x); }

#define MFMA(a, b, c) __builtin_amdgcn_mfma_f32_16x16x32_bf16((a), (b), (c), 0, 0, 0)
#define SWZ(byteoff, row) ((byteoff) ^ (((row) & 7) << 4))

// ---------------------------------------------------------------------------
// Phase K: per (chunk, bh) block. 4 waves; wave owns a 16-row strip for the
// P pass and the m-tile (wid) for buf1 accumulation (no cross-wave reduce).
//   P[row][m] = mfma(Kscaled, projT) ; e = exp2(P - h)
//   buf1[m][c] += mfma(E_T, [V,1])   via LDS-transposed eT[m][row], vT[c][row]
// v is loaded as float4 ROW fragments (like k) and transposed via 16 u16
// LDS scatter-stores -- the 16-dword global gather it replaces was the
// latency serializer (20 vmem instr/tile @ 100 VGPRs).
// ---------------------------------------------------------------------------
__global__ void __launch_bounds__(256)
fa_k(const float* __restrict__ ks, const float* __restrict__ vs,
     const float* __restrict__ proj, float* __restrict__ partial,
     int nch, int ktiles)
{
    const int chunk = blockIdx.x;
    const int bh    = blockIdx.y;
    const int b = bh >> 3, h = bh & 7;
    const int tid = threadIdx.x, wid = tid >> 6, lane = tid & 63;
    const int l15 = lane & 15, g = lane >> 4;

    __shared__ __align__(16) char eTb[2][M_ * TILE * 2];   // [m][row] bf16, swz by m
    __shared__ __align__(16) char vTb[2][D_ * TILE * 2];   // [c][row] bf16, swz by c

    const int rows = ktiles * TILE;
    const int s0 = chunk * rows;
    const size_t rs = (size_t)H_ * D_;
    const float* kb = ks + ((size_t)b * S_ * H_ + h) * D_;
    const float* vb = vs + ((size_t)b * S_ * H_ + h) * D_;

    // proj B-fragments: B[k=d][n=m]: lane: m = mt*16+l15, d = g*8+j (+32*kk)
    bf16x8 pf[4][2];
#pragma unroll
    for (int mt = 0; mt < 4; ++mt)
#pragma unroll
        for (int kk = 0; kk < 2; ++kk) {
            const float* p = proj + (mt * 16 + l15) * D_ + kk * 32 + g * 8;
            float4 a = *(const float4*)p, c = *(const float4*)(p + 4);
            union { bf16x8 v; unsigned int u[4]; } F;
            F.u[0] = pkbf(a.x, a.y); F.u[1] = pkbf(a.z, a.w);
            F.u[2] = pkbf(c.x, c.y); F.u[3] = pkbf(c.z, c.w);
            pf[mt][kk] = F.v;
        }

    // ones-column B-frag (c-tile 4): B[k][c]=1 iff c==64  (lane l15==0)
    bf16x8 onef = {0, 0, 0, 0, 0, 0, 0, 0};
    if (l15 == 0) {
#pragma unroll
        for (int j = 0; j < 8; ++j) onef[j] = (short)0x3F80;
    }

    f32x4 acc[5];
#pragma unroll
    for (int ci = 0; ci < 5; ++ci) acc[ci] = (f32x4){0.f, 0.f, 0.f, 0.f};

    auto loadT = [&](int t, float4* kp, float4* vp) {
        int sb = s0 + t * TILE;
        const float* krow = kb + (size_t)(sb + wid * 16 + l15) * rs;
        kp[0] = *(const float4*)(krow + g * 8);
        kp[1] = *(const float4*)(krow + g * 8 + 4);
        kp[2] = *(const float4*)(krow + 32 + g * 8);
        kp[3] = *(const float4*)(krow + 32 + g * 8 + 4);
        const float* vrow = vb + (size_t)(sb + wid * 16 + l15) * rs;
        vp[0] = *(const float4*)(vrow + g * 8);
        vp[1] = *(const float4*)(vrow + g * 8 + 4);
        vp[2] = *(const float4*)(vrow + 32 + g * 8);
        vp[3] = *(const float4*)(vrow + 32 + g * 8 + 4);
    };

    auto body = [&](int t, int p, const float4* kc, const float4* vc,
                    float4* kn, float4* vn) {
        if (t + 1 < ktiles) loadT(t + 1, kn, vn);

        // scale + h for row (wid*16 + l15)
        float kx[16];
#pragma unroll
        for (int i = 0; i < 4; ++i) {
            kx[4 * i + 0] = kc[i].x * XS_; kx[4 * i + 1] = kc[i].y * XS_;
            kx[4 * i + 2] = kc[i].z * XS_; kx[4 * i + 3] = kc[i].w * XS_;
        }
        float sq = 0.f;
#pragma unroll
        for (int j = 0; j < 16; ++j) sq += kx[j] * kx[j];
        sq += __shfl_xor(sq, 16);
        sq += __shfl_xor(sq, 32);
        float hrow = sq * HS_ + 3.0f;

        union { bf16x8 v; unsigned int u[4]; } A0, A1;
#pragma unroll
        for (int i = 0; i < 4; ++i) {
            A0.u[i] = pkbf(kx[2 * i], kx[2 * i + 1]);
            A1.u[i] = pkbf(kx[8 + 2 * i], kx[9 + 2 * i]);
        }

        f32x4 pa[4];
#pragma unroll
        for (int mt = 0; mt < 4; ++mt) {
            pa[mt] = (f32x4){0.f, 0.f, 0.f, 0.f};
            pa[mt] = MFMA(A0.v, pf[mt][0], pa[mt]);
            pa[mt] = MFMA(A1.v, pf[mt][1], pa[mt]);
        }

        float hr[4];
#pragma unroll
        for (int r = 0; r < 4; ++r) hr[r] = __shfl(hrow, 4 * g + r);

        char* etp = eTb[p];
        char* vtp = vTb[p];
#pragma unroll
        for (int mt = 0; mt < 4; ++mt) {
            float e0 = fexp2(pa[mt][0] - hr[0]);
            float e1 = fexp2(pa[mt][1] - hr[1]);
            float e2 = fexp2(pa[mt][2] - hr[2]);
            float e3 = fexp2(pa[mt][3] - hr[3]);
            unsigned long long pk = (unsigned long long)pkbf(e0, e1)
                                  | ((unsigned long long)pkbf(e2, e3) << 32);
            int m = mt * 16 + l15;
            *(unsigned long long*)(etp + SWZ(m * 128 + 32 * wid + 8 * g, m)) = pk;
        }
        {
            // transpose v into vT[c][row]: 16 u16 scatter stores
            int row = wid * 16 + l15;
            float vv[16];
#pragma unroll
            for (int i = 0; i < 4; ++i) {
                vv[4 * i + 0] = vc[i].x; vv[4 * i + 1] = vc[i].y;
                vv[4 * i + 2] = vc[i].z; vv[4 * i + 3] = vc[i].w;
            }
#pragma unroll
            for (int q = 0; q < 4; ++q) {
                int c0 = g * 8 + 2 * q;
                unsigned int pA = pkbf(vv[2 * q], vv[2 * q + 1]);
                *(unsigned short*)(vtp + SWZ(c0 * 128 + 2 * row, c0)) =
                    (unsigned short)pA;
                *(unsigned short*)(vtp + SWZ((c0 + 1) * 128 + 2 * row, c0 + 1)) =
                    (unsigned short)(pA >> 16);
                int c1 = 32 + c0;
                unsigned int pB = pkbf(vv[8 + 2 * q], vv[9 + 2 * q]);
                *(unsigned short*)(vtp + SWZ(c1 * 128 + 2 * row, c1)) =
                    (unsigned short)pB;
                *(unsigned short*)(vtp + SWZ((c1 + 1) * 128 + 2 * row, c1 + 1)) =
                    (unsigned short)(pB >> 16);
            }
        }
        __syncthreads();

        bf16x8 a2[2];
        {
            int m = wid * 16 + l15;
            a2[0] = *(const bf16x8*)(etp + SWZ(m * 128 + 16 * g, m));
            a2[1] = *(const bf16x8*)(etp + SWZ(m * 128 + 16 * g + 64, m));
        }
#pragma unroll
        for (int ci = 0; ci < 4; ++ci) {
            int c = ci * 16 + l15;
            bf16x8 b0 = *(const bf16x8*)(vtp + SWZ(c * 128 + 16 * g, c));
            bf16x8 b1 = *(const bf16x8*)(vtp + SWZ(c * 128 + 16 * g + 64, c));
            acc[ci] = MFMA(a2[0], b0, acc[ci]);
            acc[ci] = MFMA(a2[1], b1, acc[ci]);
        }
        acc[4] = MFMA(a2[0], onef, acc[4]);
        acc[4] = MFMA(a2[1], onef, acc[4]);
    };

    float4 ka[4], kb2[4];
    float4 va[4], vb2[4];
    loadT(0, ka, va);
    for (int t = 0; t + 2 <= ktiles; t += 2) {
        body(t, 0, ka, va, kb2, vb2);
        body(t + 1, 1, kb2, vb2, ka, va);
    }

    // store partials: D[m][c]: m = wid*16 + 4g + r, c = ci*16 + l15
    float* dst = partial + ((size_t)bh * nch + chunk) * (M_ * CPK_);
#pragma unroll
    for (int ci = 0; ci < 5; ++ci)
#pragma unroll
        for (int r = 0; r < 4; ++r)
            dst[(wid * 16 + 4 * g + r) * CPK_ + ci * 16 + l15] = acc[ci][r];
}

// ---------------------------------------------------------------------------
// Reduce partials over chunks -> buf1[bh][m][CPK_]
// ---------------------------------------------------------------------------
__global__ void __launch_bounds__(256)
fa_r(const float* __restrict__ partial, float* __restrict__ buf1, int nch)
{
    int e = blockIdx.x * 256 + threadIdx.x;
    if (e >= BH_ * M_ * CPK_) return;
    int bh = e / (M_ * CPK_);
    int r  = e - bh * (M_ * CPK_);
    const float* src = partial + (size_t)bh * nch * (M_ * CPK_) + r;
    float s0 = 0.f, s1 = 0.f, s2 = 0.f, s3 = 0.f;
    int ch = 0;
    for (; ch + 4 <= nch; ch += 4) {
        s0 += src[(size_t)(ch + 0) * (M_ * CPK_)];
        s1 += src[(size_t)(ch + 1) * (M_ * CPK_)];
        s2 += src[(size_t)(ch + 2) * (M_ * CPK_)];
        s3 += src[(size_t)(ch + 3) * (M_ * CPK_)];
    }
    for (; ch < nch; ++ch) s0 += src[(size_t)ch * (M_ * CPK_)];
    buf1[e] = (s0 + s1) + (s2 + s3);
}

// ---------------------------------------------------------------------------
// Phase Q: P = mfma(Qscaled, projT); e = exp2(P - h);
// Out^T-tiles: D[c][qrow] = mfma(buf1T, E_T); den = row c=64; out = num/den.
// ---------------------------------------------------------------------------
__global__ void __launch_bounds__(256)
fa_q(const float* __restrict__ qs, const float* __restrict__ proj,
     const float* __restrict__ buf1, float* __restrict__ out)
{
    const int chunk = blockIdx.x;
    const int bh    = blockIdx.y;
    const int b = bh >> 3, h = bh & 7;
    const int tid = threadIdx.x, wid = tid >> 6, lane = tid & 63;
    const int l15 = lane & 15, g = lane >> 4;

    __shared__ __align__(16) char eLb[2][TILE * M_ * 2];   // [qrow][m] bf16, swz by qrow
    __shared__ __align__(16) char b1tb[CPK_ * M_ * 2];     // [c][m] bf16, swz by c

    const int rows = S_ / NCHQ;
    const int s0 = chunk * rows;
    const size_t rs = (size_t)H_ * D_;
    const float* qb = qs + ((size_t)b * S_ * H_ + h) * D_;

    // stage buf1^T into LDS (c rows 65..79 are zeros in buf1 already)
    const float* b1 = buf1 + (size_t)bh * (M_ * CPK_);
    for (int i = tid; i < M_ * CPK_; i += 256) {
        int m = i / CPK_, c = i - m * CPK_;
        *(unsigned short*)(b1tb + SWZ(c * 128 + 2 * m, c)) = f2bf(b1[i]);
    }

    bf16x8 pf[4][2];
#pragma unroll
    for (int mt = 0; mt < 4; ++mt)
#pragma unroll
        for (int kk = 0; kk < 2; ++kk) {
            const float* p = proj + (mt * 16 + l15) * D_ + kk * 32 + g * 8;
            float4 a = *(const float4*)p, c = *(const float4*)(p + 4);
            union { bf16x8 v; unsigned int u[4]; } F;
            F.u[0] = pkbf(a.x, a.y); F.u[1] = pkbf(a.z, a.w);
            F.u[2] = pkbf(c.x, c.y); F.u[3] = pkbf(c.z, c.w);
            pf[mt][kk] = F.v;
        }
    __syncthreads();

    // buf1^T A-fragments, read once: A[c][m]: c = ci*16+l15, m = g*8+j (+32*kk)
    bf16x8 af3[5][2];
#pragma unroll
    for (int ci = 0; ci < 5; ++ci)
#pragma unroll
        for (int kk = 0; kk < 2; ++kk) {
            int c = ci * 16 + l15;
            af3[ci][kk] = *(const bf16x8*)(b1tb + SWZ(c * 128 + 16 * g + 64 * kk, c));
        }

    auto loadQ = [&](int t, float4* qp) {
        int sb = s0 + t * TILE;
        const float* qrow = qb + (size_t)(sb + wid * 16 + l15) * rs;
        qp[0] = *(const float4*)(qrow + g * 8);
        qp[1] = *(const float4*)(qrow + g * 8 + 4);
        qp[2] = *(const float4*)(qrow + 32 + g * 8);
        qp[3] = *(const float4*)(qrow + 32 + g * 8 + 4);
    };

    auto body = [&](int t, int p, const float4* qc, float4* qn) {
        if (t + 1 < QTILES) loadQ(t + 1, qn);

        float kx[16];
#pragma unroll
        for (int i = 0; i < 4; ++i) {
            kx[4 * i + 0] = qc[i].x * XS_; kx[4 * i + 1] = qc[i].y * XS_;
            kx[4 * i + 2] = qc[i].z * XS_; kx[4 * i + 3] = qc[i].w * XS_;
        }
        float sq = 0.f;
#pragma unroll
        for (int j = 0; j < 16; ++j) sq += kx[j] * kx[j];
        sq += __shfl_xor(sq, 16);
        sq += __shfl_xor(sq, 32);
        float hrow = sq * HS_ + 3.0f;

        union { bf16x8 v; unsigned int u[4]; } A0, A1;
#pragma unroll
        for (int i = 0; i < 4; ++i) {
            A0.u[i] = pkbf(kx[2 * i], kx[2 * i + 1]);
            A1.u[i] = pkbf(kx[8 + 2 * i], kx[9 + 2 * i]);
        }

        f32x4 pa[4];
#pragma unroll
        for (int mt = 0; mt < 4; ++mt) {
            pa[mt] = (f32x4){0.f, 0.f, 0.f, 0.f};
            pa[mt] = MFMA(A0.v, pf[mt][0], pa[mt]);
            pa[mt] = MFMA(A1.v, pf[mt][1], pa[mt]);
        }

        float hr[4];
#pragma unroll
        for (int r = 0; r < 4; ++r) hr[r] = __shfl(hrow, 4 * g + r);

        char* elp = eLb[p];
#pragma unroll
        for (int mt = 0; mt < 4; ++mt) {
            int m = mt * 16 + l15;
            float e0 = fexp2(pa[mt][0] - hr[0]);
            float e1 = fexp2(pa[mt][1] - hr[1]);
            float e2 = fexp2(pa[mt][2] - hr[2]);
            float e3 = fexp2(pa[mt][3] - hr[3]);
            unsigned int p01 = pkbf(e0, e1), p23 = pkbf(e2, e3);
            int q0 = wid * 16 + 4 * g;
            *(unsigned short*)(elp + SWZ((q0 + 0) * 128 + 2 * m, q0 + 0)) =
                (unsigned short)p01;
            *(unsigned short*)(elp + SWZ((q0 + 1) * 128 + 2 * m, q0 + 1)) =
                (unsigned short)(p01 >> 16);
            *(unsigned short*)(elp + SWZ((q0 + 2) * 128 + 2 * m, q0 + 2)) =
                (unsigned short)p23;
            *(unsigned short*)(elp + SWZ((q0 + 3) * 128 + 2 * m, q0 + 3)) =
                (unsigned short)(p23 >> 16);
        }
        __syncthreads();

        bf16x8 b3[2];
        {
            int qrow = wid * 16 + l15;
            b3[0] = *(const bf16x8*)(elp + SWZ(qrow * 128 + 16 * g, qrow));
            b3[1] = *(const bf16x8*)(elp + SWZ(qrow * 128 + 16 * g + 64, qrow));
        }
        f32x4 dt[5];
#pragma unroll
        for (int ci = 0; ci < 5; ++ci) {
            dt[ci] = (f32x4){0.f, 0.f, 0.f, 0.f};
            dt[ci] = MFMA(af3[ci][0], b3[0], dt[ci]);
            dt[ci] = MFMA(af3[ci][1], b3[1], dt[ci]);
        }

        float den = __shfl(dt[4][0], l15);      // lanes g==0 hold den[qrow=l15]
        float rd = 1.0f / fmaxf(den, EPS_);

        int sg = s0 + t * TILE + wid * 16 + l15;
        size_t base = (((size_t)b * S_ + sg) * H_ + h) * D_;
#pragma unroll
        for (int ci = 0; ci < 4; ++ci) {
            f32x4 o;
#pragma unroll
            for (int r = 0; r < 4; ++r) o[r] = dt[ci][r] * rd;
            *(f32x4*)(out + base + ci * 16 + 4 * g) = o;
        }
    };

    float4 qa[4], qb2[4];
    loadQ(0, qa);
    for (int t = 0; t < QTILES; t += 2) {
        body(t, 0, qa, qb2);
        body(t + 1, 1, qb2, qa);
    }
}

extern "C" void kernel_launch(void* const* d_in, const int* in_sizes, int n_in,
                              void* d_out, int out_size, void* d_ws, size_t ws_size,
                              hipStream_t stream)
{
    const float* qs   = (const float*)d_in[0];
    const float* ks   = (const float*)d_in[1];
    const float* vs   = (const float*)d_in[2];
    const float* proj = (const float*)d_in[3];
    float* out = (float*)d_out;

    int nch = 16;
    while (nch > 8 &&
           (size_t)BH_ * (size_t)(nch + 1) * (M_ * CPK_) * sizeof(float) > ws_size)
        nch >>= 1;
    int ktiles = S_ / nch / TILE;                 // 8 (or 16)

    float* partial = (float*)d_ws;                // BH*nch*M*CPK
    float* buf1 = partial + (size_t)BH_ * nch * (M_ * CPK_);

    fa_k<<<dim3(nch, BH_), 256, 0, stream>>>(ks, vs, proj, partial, nch, ktiles);
    int nred = (BH_ * M_ * CPK_ + 255) / 256;
    fa_r<<<dim3(nred), 256, 0, stream>>>(partial, buf1, nch);
    fa_q<<<dim3(NCHQ, BH_), 256, 0, stream>>>(qs, proj, buf1, out);
}